// Round 8
// baseline (466.522 us; speedup 1.0000x reference)
//
#include <hip/hip_runtime.h>
#include <stdint.h>

// ---------------------------------------------------------------------------
// MD5Surrogate: 64-round scan of 3-layer MLP (22->256->256->16), B=16384.
// fp32 in/out. R18 = R17 + LDS piecewise-linear gelu table:
//  gelu_f (~10 VALU + 2 TRANS ops, ~30 issue slots) was ~half the VALU
//  budget (32 evals/lane/round; VALU pipe is the measured floor at ~54%
//  busy). Replaced in L1/L2 with a 1024-segment linear table on [-8,8]:
//  gelu(x) ~= a_i + b_i*x, i = clamp(trunc(64x+512)) -> fma,max,cvt,min,
//  ds_read_b64,fma = ~6 VALU + 1 LDS op. Edge segments extrapolate exactly
//  (b~1,a~0 above; b~0,a~0 below) so no eval clamp. Interp err 2.4e-5 +
//  build err 2.5e-5 << 2e-3 bf16-h-storage error that sets absmax.
//  Table built in prologue via gelu_f, +8KB LDS (55KB/block, still 2/CU).
// From R17: cross-barrier prefetch of a1/bb1/bb2 (20 VGPRs, uniform),
// L3 SIMD-parity balance (even blocks waves{0,1}, odd {2,3}).
// From R14: distributed L3 (a3/bb3 live range contained inside branch -> no
// spill), word scatter on own wave, barrier D publishes x, bf16 hi/lo x,
// bias-in-accumulator, a2 per-tt in-loop.
// Occupancy ladder closed: R11/R15/R16 all lost to 2 domains x 8w x NG=2.
// ---------------------------------------------------------------------------

using bf16x8   = __attribute__((ext_vector_type(8))) __bf16;
using floatx4  = __attribute__((ext_vector_type(4))) float;
using ushort4v = __attribute__((ext_vector_type(4))) unsigned short;

__constant__ int c_sched[64] = {
  0,1,2,3,4,5,6,7,8,9,10,11,12,13,14,15,
  1,6,11,0,5,10,15,4,9,14,3,8,13,2,7,12,
  5,8,11,14,1,4,7,10,13,0,3,6,9,12,15,2,
  0,7,14,5,12,3,10,1,8,15,6,13,4,11,2,9
};
__constant__ float c_shift[64] = {
  7,12,17,22,7,12,17,22,7,12,17,22,7,12,17,22,
  5,9,14,20,5,9,14,20,5,9,14,20,5,9,14,20,
  4,11,16,23,4,11,16,23,4,11,16,23,4,11,16,23,
  6,10,15,21,6,10,15,21,6,10,15,21,6,10,15,21
};

__device__ __forceinline__ unsigned short bfbits(__bf16 b) {
  union { __bf16 b; unsigned short u; } v; v.b = b; return v.u;
}
// gelu via A&S 7.1.25 (|eps|<=2.5e-5) -- used only to BUILD the LDS table
__device__ __forceinline__ float gelu_f(float x) {
  float ax = fabsf(x);
  float t  = __builtin_amdgcn_rcpf(__builtin_fmaf(0.33270222f, ax, 1.0f));
  float e  = __builtin_amdgcn_exp2f(x * x * -0.72134752f);
  float poly = t * __builtin_fmaf(t, __builtin_fmaf(t, 0.7478556f, -0.0958798f),
                                  0.3480242f);
  float er = __builtin_fmaf(-poly, e, 1.0f);
  er = copysignf(er, x);
  float hx = 0.5f * x;
  return __builtin_fmaf(hx, er, hx);
}
// table lookup gelu: ~6 VALU + 1 ds_read_b64
__device__ __forceinline__ float gelu_tab(const float2* __restrict__ t, float x) {
  float s = __builtin_fmaf(x, 64.0f, 512.0f);
  s = fmaxf(s, 0.0f);
  int i = (int)s;                 // trunc; s >= 0
  i = i > 1023 ? 1023 : i;
  float2 ab = t[i];
  return __builtin_fmaf(ab.y, x, ab.x);
}
__device__ __forceinline__ floatx4 mfma16(bf16x8 a, bf16x8 b, floatx4 c) {
  return __builtin_amdgcn_mfma_f32_16x16x32_bf16(a, b, c, 0, 0, 0);
}
struct BfPair { unsigned short h, l; };
__device__ __forceinline__ BfPair split2(float s) {
  __bf16 hb = (__bf16)s;
  __bf16 lb = (__bf16)(s - (float)hb);
  BfPair p; p.h = bfbits(hb); p.l = bfbits(lb); return p;
}

// ---------------------------------------------------------------------------
// Packed-weight layout: fragment = 64 lanes x 8 bf16. A[m][k]: m=lane&15,
// k=8*(lane>>4)+j.  P1 (r*16+t): W1[r][k][16t+m] (k>=22 -> 0)
//                   P2 ((r*16+t)*8+c): W2[r][32c+k'][16t+m]
//                   P3 (r*8+c): W3[r][32c+k'][m]
// ---------------------------------------------------------------------------
#define N1G (64*16*64)
#define N2G (64*16*8*64)
#define N3G (64*8*64)

__global__ void pack_w(const float* __restrict__ W1,
                       const float* __restrict__ W2,
                       const float* __restrict__ W3,
                       unsigned short* __restrict__ P) {
  int gid = blockIdx.x * blockDim.x + threadIdx.x;
  if (gid >= N1G + N2G + N3G) return;
  unsigned short v[8];
  unsigned short* dst;
  if (gid < N1G) {
    int lane = gid & 63, t = (gid >> 6) & 15, r = gid >> 10;
    int qq = lane >> 4, mm = lane & 15;
    #pragma unroll
    for (int j = 0; j < 8; ++j) {
      int k = 8*qq + j;
      v[j] = (k < 22) ? bfbits((__bf16)W1[(r*22 + k)*256 + 16*t + mm]) : (unsigned short)0;
    }
    dst = P + (size_t)gid * 8;
  } else if (gid < N1G + N2G) {
    int g = gid - N1G;
    int lane = g & 63, c = (g >> 6) & 7, t = (g >> 9) & 15, r = g >> 13;
    int qq = lane >> 4, mm = lane & 15;
    #pragma unroll
    for (int j = 0; j < 8; ++j) {
      int k = 32*c + 8*qq + j;
      v[j] = bfbits((__bf16)W2[((size_t)r*256 + k)*256 + 16*t + mm]);
    }
    dst = P + (size_t)(N1G + g) * 8;
  } else {
    int g = gid - N1G - N2G;
    int lane = g & 63, c = (g >> 6) & 7, r = g >> 9;
    int qq = lane >> 4, mm = lane & 15;
    #pragma unroll
    for (int j = 0; j < 8; ++j) {
      int k = 32*c + 8*qq + j;
      v[j] = bfbits((__bf16)W3[(r*256 + k)*16 + mm]);
    }
    dst = P + (size_t)(N1G + N2G + g) * 8;
  }
  ushort4v lo = { v[0],v[1],v[2],v[3] }, hi = { v[4],v[5],v[6],v[7] };
  *(ushort4v*)dst = lo;
  *(ushort4v*)(dst + 4) = hi;
}

// ---------------------------------------------------------------------------
#define NG  2    // row-groups per block (32 rows/block)
#define TT  2    // feature sub-tiles per wave (8 waves x 32 features = 256)
#define SXW 36   // x row stride (ushorts)
#define SH 264   // h row stride
#define SM 66    // msg row stride

__global__ __launch_bounds__(512, 4) void md5_main(
    const float* __restrict__ msg,   // (16384,64)
    const float* __restrict__ st0,   // (16384,16)
    const float* __restrict__ b1,    // (64,256)
    const float* __restrict__ b2,    // (64,256)
    const float* __restrict__ b3,    // (64,16)
    const unsigned short* __restrict__ P,
    float* __restrict__ out)         // (16384,16)
{
  __shared__ unsigned short xh[NG][16][SXW], xl[NG][16][SXW];
  __shared__ unsigned short hA[NG][16][SH], hB[NG][16][SH];
  __shared__ unsigned short msgb[NG*16][SM], msgl[NG*16][SM];
  __shared__ float2 gtab[1024];    // piecewise-linear gelu (a,b) per segment

  const int tid  = threadIdx.x;
  const int wv   = tid >> 6;        // 0..7
  const int lane = tid & 63;
  const int q    = lane >> 4;
  const int ln   = lane & 15;
  const int row0 = blockIdx.x * (NG*16);
  const int l3w  = (blockIdx.x & 1) << 1;   // L3 waves {l3w, l3w+1}
  const int scw  = l3w ^ 2;                 // scatter wave on the other SIMD pair

  const unsigned short* P1 = P;
  const unsigned short* P2 = P + (size_t)N1G * 8;
  const unsigned short* P3 = P + (size_t)(N1G + N2G) * 8;

  // build gelu table: 1024 segments on [-8,8], h = 1/64
  for (int i = tid; i < 1024; i += 512) {
    float x0 = __builtin_fmaf((float)i, 0.015625f, -8.0f);
    float y0 = gelu_f(x0);
    float y1 = gelu_f(x0 + 0.015625f);
    float b  = (y1 - y0) * 64.0f;
    gtab[i]  = make_float2(__builtin_fmaf(-b, x0, y0), b);
  }
  // zero x buffers once (pad cols 22..35 must stay 0 forever)
  for (int i = tid; i < NG*16*SXW; i += 512) {
    (&xh[0][0][0])[i] = 0; (&xl[0][0][0])[i] = 0;
  }
  // msg preload (shared, hi/lo): 32 rows x 64 = 2048 elems / 512 thr = 4 each
  {
    int idx = tid * 4, rr = idx >> 6, cc = idx & 63;
    floatx4 v0 = *(const floatx4*)(msg + (size_t)(row0 + rr)*64 + cc);
    #pragma unroll
    for (int j = 0; j < 4; ++j) {
      BfPair p0 = split2(v0[j]);
      msgb[rr][cc + j] = p0.h;  msgl[rr][cc + j] = p0.l;
    }
  }
  // init state: one wave suffices (ordered by the barrier below)
  if (wv == 0) {
    #pragma unroll
    for (int g = 0; g < NG; ++g) {
      floatx4 v = *(const floatx4*)(st0 + (size_t)(row0 + g*16 + ln)*16 + 4*q);
      ushort4v h4, l4;
      #pragma unroll
      for (int e = 0; e < 4; ++e) { BfPair p = split2(v[e]); h4[e] = p.h; l4[e] = p.l; }
      *(ushort4v*)&xh[g][ln][4*q] = h4;
      *(ushort4v*)&xl[g][ln][4*q] = l4;
    }
  }
  __syncthreads();   // gtab + msgb/msgl + state + zero-pads ready
  // round-0 word+rinfo: every wave writes the full (identical) set so its own
  // L1 reads are covered without another barrier (benign identical-value race)
  if (lane < NG*16) {
    int g = lane >> 4, n = lane & 15, rrow = lane;
    int s = c_sched[0];
    BfPair i1p = split2(c_shift[0] / 25.0f);
    #pragma unroll
    for (int j = 0; j < 4; ++j) {
      xh[g][n][16+j] = msgb[rrow][4*s+j];
      xl[g][n][16+j] = msgl[rrow][4*s+j];
    }
    xh[g][n][20] = 0;     xl[g][n][20] = 0;   // round 0: i/64 = 0
    xh[g][n][21] = i1p.h; xl[g][n][21] = i1p.l;
  }

  // ---- prefetched regs for round r: a1/bb1 (L1) + bb2 (L2 acc init) ----
  bf16x8  a1c[TT];  floatx4 bb1c[TT], bb2c[TT];
  {
    const unsigned short* p1 = P1 + ((size_t)(TT*wv)*64 + lane)*8;
    #pragma unroll
    for (int tt = 0; tt < TT; ++tt) {
      a1c[tt]  = *(const bf16x8*)(p1 + (size_t)tt*512);
      bb1c[tt] = *(const floatx4*)(b1 + (TT*wv + tt)*16 + 4*q);
      bb2c[tt] = *(const floatx4*)(b2 + (TT*wv + tt)*16 + 4*q);
    }
  }

  #pragma unroll 1
  for (int r = 0; r < 64; ++r) {
    // -------- Layer 1: x @ W1 -> h1 (own 32-feature slice, both groups) ----
    bf16x8 bxh[NG], bxl[NG];
    #pragma unroll
    for (int g = 0; g < NG; ++g) {
      bxh[g] = *(const bf16x8*)&xh[g][ln][8*q];
      bxl[g] = *(const bf16x8*)&xl[g][ln][8*q];
    }
    #pragma unroll
    for (int tt = 0; tt < TT; ++tt) {
      int f0 = (TT*wv + tt)*16 + 4*q;
      #pragma unroll
      for (int g = 0; g < NG; ++g) {
        floatx4 acc = bb1c[tt];
        acc = mfma16(a1c[tt], bxl[g], acc);
        acc = mfma16(a1c[tt], bxh[g], acc);
        ushort4v h4;
        #pragma unroll
        for (int e = 0; e < 4; ++e) h4[e] = bfbits((__bf16)gelu_tab(gtab, acc[e]));
        *(ushort4v*)&hA[g][ln][f0] = h4;
      }
    }
    __syncthreads();                       // (B) h1 ready; hB free

    // -------- Layer 2: h1 @ W2 -> h2 (own slice, both groups) --------
    bf16x8 Bf[NG][8];
    #pragma unroll
    for (int g = 0; g < NG; ++g)
      #pragma unroll
      for (int c = 0; c < 8; ++c) Bf[g][c] = *(const bf16x8*)&hA[g][ln][32*c + 8*q];

    const unsigned short* p2 = P2 + ((size_t)((r*16 + TT*wv)*8)*64 + lane)*8;
    #pragma unroll
    for (int tt = 0; tt < TT; ++tt) {
      bf16x8 a2[8];
      #pragma unroll
      for (int c = 0; c < 8; ++c)
        a2[c] = *(const bf16x8*)(p2 + (size_t)(tt*8 + c)*512);
      int f0 = (TT*wv + tt)*16 + 4*q;
      #pragma unroll
      for (int g = 0; g < NG; ++g) {
        floatx4 acc = bb2c[tt];
        #pragma unroll
        for (int c = 0; c < 8; ++c) acc = mfma16(a2[c], Bf[g][c], acc);
        ushort4v h4;
        #pragma unroll
        for (int e = 0; e < 4; ++e) h4[e] = bfbits((__bf16)gelu_tab(gtab, acc[e]));
        *(ushort4v*)&hB[g][ln][f0] = h4;
      }
    }
    __syncthreads();                       // (C) h2 ready

    // -------- prefetch next round's a1/bb1/bb2 (hides under L3 + barrier D)
    if (r < 63) {
      const unsigned short* p1n = P1 + ((size_t)((r+1)*16 + TT*wv)*64 + lane)*8;
      #pragma unroll
      for (int tt = 0; tt < TT; ++tt) {
        a1c[tt]  = *(const bf16x8*)(p1n + (size_t)tt*512);
        bb1c[tt] = *(const floatx4*)(b1 + (r+1)*256 + (TT*wv + tt)*16 + 4*q);
        bb2c[tt] = *(const floatx4*)(b2 + (r+1)*256 + (TT*wv + tt)*16 + 4*q);
      }
    }

    // -------- Layer 3 (distributed; SIMD-parity-balanced wave pair) --------
    if (wv == l3w || wv == l3w + 1) {
      const int g = wv - l3w;
      const unsigned short* p3 = P3 + ((size_t)(r*8)*64 + lane)*8;
      bf16x8 a3[8];
      #pragma unroll
      for (int c = 0; c < 8; ++c) a3[c] = *(const bf16x8*)(p3 + (size_t)c*512);
      floatx4 s = *(const floatx4*)(b3 + r*16 + 4*q);
      #pragma unroll
      for (int c = 0; c < 8; ++c) {
        bf16x8 bh = *(const bf16x8*)&hB[g][ln][32*c + 8*q];
        s = mfma16(a3[c], bh, s);
      }
      if (r == 63) {
        *(floatx4*)(out + (size_t)(row0 + g*16 + ln)*16 + 4*q) = s;
      } else {
        ushort4v h4, l4;
        #pragma unroll
        for (int e = 0; e < 4; ++e) { BfPair p = split2(s[e]); h4[e] = p.h; l4[e] = p.l; }
        *(ushort4v*)&xh[g][ln][4*q] = h4;
        *(ushort4v*)&xl[g][ln][4*q] = l4;
      }
    }
    // word + rinfo for next round: scatter wave (other SIMD pair)
    if (wv == scw && lane < NG*16 && r < 63) {
      int g = lane >> 4, n = lane & 15, rrow = lane;
      int sc = c_sched[r+1];
      float i0 = (float)(r+1) * 0.015625f;   // exact in bf16
      BfPair i1p = split2(c_shift[r+1] / 25.0f);
      #pragma unroll
      for (int j = 0; j < 4; ++j) {
        xh[g][n][16+j] = msgb[rrow][4*sc+j];
        xl[g][n][16+j] = msgl[rrow][4*sc+j];
      }
      xh[g][n][20] = bfbits((__bf16)i0); xl[g][n][20] = 0;
      xh[g][n][21] = i1p.h;              xl[g][n][21] = i1p.l;
    }
    if (r < 63) __syncthreads();           // (D) x ready for next L1
  }
}

// ---------------------------------------------------------------------------
extern "C" void kernel_launch(void* const* d_in, const int* in_sizes, int n_in,
                              void* d_out, int out_size, void* d_ws, size_t ws_size,
                              hipStream_t stream) {
  const float* msg = (const float*)d_in[0];
  const float* st0 = (const float*)d_in[1];
  const float* W1  = (const float*)d_in[2];
  const float* b1  = (const float*)d_in[3];
  const float* W2  = (const float*)d_in[4];
  const float* b2  = (const float*)d_in[5];
  const float* W3  = (const float*)d_in[6];
  const float* b3  = (const float*)d_in[7];
  float* out = (float*)d_out;
  (void)in_sizes; (void)n_in; (void)out_size; (void)ws_size;

  unsigned short* P = (unsigned short*)d_ws;
  const int totalGroups = N1G + N2G + N3G;   // 622592
  pack_w<<<(totalGroups + 255) / 256, 256, 0, stream>>>(W1, W2, W3, P);
  md5_main<<<512, 512, 0, stream>>>(msg, st0, b1, b2, b3, P, out);
}

// Round 10
// 408.600 us; speedup vs baseline: 1.1418x; 1.1418x over previous
//
#include <hip/hip_runtime.h>
#include <stdint.h>

// ---------------------------------------------------------------------------
// MD5Surrogate: 64-round scan of 3-layer MLP (22->256->256->16), B=16384.
// fp32 in/out. R20 = R19 (fp16 datapath) with the cvt_pkrtz return-type fix:
//  __builtin_amdgcn_cvt_pkrtz returns __fp16x2 on this clang -> bit-cast
//  through a union to our _Float16x2.
//  - R18 ablation proved the kernel is critical-path-bound, with gelu issue
//    (~204us) the dominant term; its LDS-table fix added latency and lost.
//  - fp16 (10-bit mantissa) vs bf16 (7-bit): weights + h storage get 8x more
//    precise, so the x hi/lo split is dropped (single fp16 x), halving L1
//    MFMA (8->4/wave) and killing split2 everywhere.
//  - gelu computed per PAIR: t,e in fp32 (rcp/exp2 trans unchanged), then
//    cvt_pkrtz packs x/t/e and poly+sign+out run as v_pk_* half2 ops
//    (~18 slots/pair vs ~29 incl old pack) -- all in-register, no table.
//  - h written as packed half2 (the pkrtz result IS the store data).
//  - MFMA: mfma_f32_16x16x32_f16 (same rate as bf16 variant).
//  - state x written with RTE scalar casts (64-round chain); h uses RTZ.
// From R17: 512thr/8 waves/NG=2/TT=2, 2 blocks/CU (2 barrier domains),
// distributed L3 (SIMD-parity wave pair, a3/bb3 live range contained -> no
// spill), word scatter on own wave, cross-barrier prefetch of a1/bb1/bb2,
// bias-in-accumulator, a2 per-tt in-loop, 3 barriers/round.
// Occupancy ladder closed (R11/R15/R16); VALU-cut-via-LDS closed (R18).
// ---------------------------------------------------------------------------

using f16x8    = __attribute__((ext_vector_type(8))) _Float16;
using f16x2    = __attribute__((ext_vector_type(2))) _Float16;
using fp16x2r  = __attribute__((ext_vector_type(2))) __fp16;  // builtin ret type
using floatx4  = __attribute__((ext_vector_type(4))) float;
using ushort4v = __attribute__((ext_vector_type(4))) unsigned short;
using uint2v   = __attribute__((ext_vector_type(2))) unsigned int;

__constant__ int c_sched[64] = {
  0,1,2,3,4,5,6,7,8,9,10,11,12,13,14,15,
  1,6,11,0,5,10,15,4,9,14,3,8,13,2,7,12,
  5,8,11,14,1,4,7,10,13,0,3,6,9,12,15,2,
  0,7,14,5,12,3,10,1,8,15,6,13,4,11,2,9
};
__constant__ float c_shift[64] = {
  7,12,17,22,7,12,17,22,7,12,17,22,7,12,17,22,
  5,9,14,20,5,9,14,20,5,9,14,20,5,9,14,20,
  4,11,16,23,4,11,16,23,4,11,16,23,4,11,16,23,
  6,10,15,21,6,10,15,21,6,10,15,21,6,10,15,21
};

__device__ __forceinline__ unsigned short f16bits(float x) {
  union { _Float16 h; unsigned short u; } v; v.h = (_Float16)x; return v.u;
}
__device__ __forceinline__ f16x2 pkrtz(float a, float b) {
  union { fp16x2r r; f16x2 h; } v; v.r = __builtin_amdgcn_cvt_pkrtz(a, b);
  return v.h;
}
#define H2(c) ((f16x2){(_Float16)(c), (_Float16)(c)})

// gelu on a PAIR of fp32 inputs -> packed fp16 pair (u32).
// A&S 7.1.25 (|eps|<=2.5e-5 in fp32; fp16 tail adds ~5e-4 abs worst-case).
// t,e in fp32 (inputs already fp32); poly/sign/out packed half2.
__device__ __forceinline__ unsigned int gelu2(float a0, float a1) {
  float t0 = __builtin_amdgcn_rcpf(__builtin_fmaf(0.33270222f, fabsf(a0), 1.0f));
  float t1 = __builtin_amdgcn_rcpf(__builtin_fmaf(0.33270222f, fabsf(a1), 1.0f));
  float e0 = __builtin_amdgcn_exp2f(a0 * a0 * -0.72134752f);
  float e1 = __builtin_amdgcn_exp2f(a1 * a1 * -0.72134752f);
  f16x2 xp = pkrtz(a0, a1);
  f16x2 tp = pkrtz(t0, t1);
  f16x2 ep = pkrtz(e0, e1);
  f16x2 poly = tp * __builtin_elementwise_fma(
                   tp, __builtin_elementwise_fma(tp, H2(0.7478556f), H2(-0.0958798f)),
                   H2(0.3480242f));
  f16x2 er = __builtin_elementwise_fma(poly, -ep, H2(1.0f));
  union { f16x2 h; unsigned int u; } ue, ux, uo;
  ue.h = er; ux.h = xp;
  uo.u = (ue.u & 0x7FFF7FFFu) | (ux.u & 0x80008000u);   // copysign(er, x)
  f16x2 hx = xp * H2(0.5f);
  union { f16x2 h; unsigned int u; } r;
  r.h = __builtin_elementwise_fma(hx, uo.h, hx);        // 0.5x(1+er)
  return r.u;
}
__device__ __forceinline__ floatx4 mfma16f(f16x8 a, f16x8 b, floatx4 c) {
  return __builtin_amdgcn_mfma_f32_16x16x32_f16(a, b, c, 0, 0, 0);
}

// ---------------------------------------------------------------------------
// Packed-weight layout (fp16): fragment = 64 lanes x 8 fp16. A[m][k]:
// m=lane&15, k=8*(lane>>4)+j.  P1 (r*16+t): W1[r][k][16t+m] (k>=22 -> 0)
//                   P2 ((r*16+t)*8+c): W2[r][32c+k'][16t+m]
//                   P3 (r*8+c): W3[r][32c+k'][m]
// ---------------------------------------------------------------------------
#define N1G (64*16*64)
#define N2G (64*16*8*64)
#define N3G (64*8*64)

__global__ void pack_w(const float* __restrict__ W1,
                       const float* __restrict__ W2,
                       const float* __restrict__ W3,
                       unsigned short* __restrict__ P) {
  int gid = blockIdx.x * blockDim.x + threadIdx.x;
  if (gid >= N1G + N2G + N3G) return;
  unsigned short v[8];
  unsigned short* dst;
  if (gid < N1G) {
    int lane = gid & 63, t = (gid >> 6) & 15, r = gid >> 10;
    int qq = lane >> 4, mm = lane & 15;
    #pragma unroll
    for (int j = 0; j < 8; ++j) {
      int k = 8*qq + j;
      v[j] = (k < 22) ? f16bits(W1[(r*22 + k)*256 + 16*t + mm]) : (unsigned short)0;
    }
    dst = P + (size_t)gid * 8;
  } else if (gid < N1G + N2G) {
    int g = gid - N1G;
    int lane = g & 63, c = (g >> 6) & 7, t = (g >> 9) & 15, r = g >> 13;
    int qq = lane >> 4, mm = lane & 15;
    #pragma unroll
    for (int j = 0; j < 8; ++j) {
      int k = 32*c + 8*qq + j;
      v[j] = f16bits(W2[((size_t)r*256 + k)*256 + 16*t + mm]);
    }
    dst = P + (size_t)(N1G + g) * 8;
  } else {
    int g = gid - N1G - N2G;
    int lane = g & 63, c = (g >> 6) & 7, r = g >> 9;
    int qq = lane >> 4, mm = lane & 15;
    #pragma unroll
    for (int j = 0; j < 8; ++j) {
      int k = 32*c + 8*qq + j;
      v[j] = f16bits(W3[(r*256 + k)*16 + mm]);
    }
    dst = P + (size_t)(N1G + N2G + g) * 8;
  }
  ushort4v lo = { v[0],v[1],v[2],v[3] }, hi = { v[4],v[5],v[6],v[7] };
  *(ushort4v*)dst = lo;
  *(ushort4v*)(dst + 4) = hi;
}

// ---------------------------------------------------------------------------
#define NG  2    // row-groups per block (32 rows/block)
#define TT  2    // feature sub-tiles per wave (8 waves x 32 features = 256)
#define SXW 32   // x row stride (fp16): 22 real + 10 zero pad (K=32)
#define SH 264   // h row stride
#define SM 66    // msg row stride

__global__ __launch_bounds__(512, 4) void md5_main(
    const float* __restrict__ msg,   // (16384,64)
    const float* __restrict__ st0,   // (16384,16)
    const float* __restrict__ b1,    // (64,256)
    const float* __restrict__ b2,    // (64,256)
    const float* __restrict__ b3,    // (64,16)
    const unsigned short* __restrict__ P,
    float* __restrict__ out)         // (16384,16)
{
  __shared__ unsigned short xh[NG][16][SXW];
  __shared__ unsigned short hA[NG][16][SH], hB[NG][16][SH];
  __shared__ unsigned short msgb[NG*16][SM];

  const int tid  = threadIdx.x;
  const int wv   = tid >> 6;        // 0..7
  const int lane = tid & 63;
  const int q    = lane >> 4;
  const int ln   = lane & 15;
  const int row0 = blockIdx.x * (NG*16);
  const int l3w  = (blockIdx.x & 1) << 1;   // L3 waves {l3w, l3w+1}
  const int scw  = l3w ^ 2;                 // scatter wave on the other SIMD pair

  const unsigned short* P1 = P;
  const unsigned short* P2 = P + (size_t)N1G * 8;
  const unsigned short* P3 = P + (size_t)(N1G + N2G) * 8;

  // zero x buffer once (pad cols 22..31 must stay 0 forever)
  for (int i = tid; i < NG*16*SXW; i += 512) (&xh[0][0][0])[i] = 0;
  // msg preload (fp16): 32 rows x 64 = 2048 elems / 512 thr = 4 each
  {
    int idx = tid * 4, rr = idx >> 6, cc = idx & 63;
    floatx4 v0 = *(const floatx4*)(msg + (size_t)(row0 + rr)*64 + cc);
    #pragma unroll
    for (int j = 0; j < 4; ++j) msgb[rr][cc + j] = f16bits(v0[j]);
  }
  // init state (fp16, RTE): one wave suffices (ordered by barrier below)
  if (wv == 0) {
    #pragma unroll
    for (int g = 0; g < NG; ++g) {
      floatx4 v = *(const floatx4*)(st0 + (size_t)(row0 + g*16 + ln)*16 + 4*q);
      ushort4v h4;
      #pragma unroll
      for (int e = 0; e < 4; ++e) h4[e] = f16bits(v[e]);
      *(ushort4v*)&xh[g][ln][4*q] = h4;
    }
  }
  __syncthreads();   // msgb + state + zero-pads ready
  // round-0 word+rinfo: every wave writes the full identical set (benign race)
  if (lane < NG*16) {
    int g = lane >> 4, n = lane & 15, rrow = lane;
    int s = c_sched[0];
    unsigned short i1b = f16bits(c_shift[0] / 25.0f);
    #pragma unroll
    for (int j = 0; j < 4; ++j) xh[g][n][16+j] = msgb[rrow][4*s+j];
    xh[g][n][20] = 0;        // round 0: i/64 = 0
    xh[g][n][21] = i1b;
  }

  // ---- prefetched regs for round r: a1/bb1 (L1) + bb2 (L2 acc init) ----
  f16x8   a1c[TT];  floatx4 bb1c[TT], bb2c[TT];
  {
    const unsigned short* p1 = P1 + ((size_t)(TT*wv)*64 + lane)*8;
    #pragma unroll
    for (int tt = 0; tt < TT; ++tt) {
      a1c[tt]  = *(const f16x8*)(p1 + (size_t)tt*512);
      bb1c[tt] = *(const floatx4*)(b1 + (TT*wv + tt)*16 + 4*q);
      bb2c[tt] = *(const floatx4*)(b2 + (TT*wv + tt)*16 + 4*q);
    }
  }

  #pragma unroll 1
  for (int r = 0; r < 64; ++r) {
    // -------- Layer 1: x @ W1 -> h1 (own 32-feature slice, both groups) ----
    f16x8 bx[NG];
    #pragma unroll
    for (int g = 0; g < NG; ++g) bx[g] = *(const f16x8*)&xh[g][ln][8*q];
    #pragma unroll
    for (int tt = 0; tt < TT; ++tt) {
      int f0 = (TT*wv + tt)*16 + 4*q;
      #pragma unroll
      for (int g = 0; g < NG; ++g) {
        floatx4 acc = mfma16f(a1c[tt], bx[g], bb1c[tt]);
        uint2v w = { gelu2(acc[0], acc[1]), gelu2(acc[2], acc[3]) };
        *(uint2v*)&hA[g][ln][f0] = w;
      }
    }
    __syncthreads();                       // (B) h1 ready; hB free

    // -------- Layer 2: h1 @ W2 -> h2 (own slice, both groups) --------
    f16x8 Bf[NG][8];
    #pragma unroll
    for (int g = 0; g < NG; ++g)
      #pragma unroll
      for (int c = 0; c < 8; ++c) Bf[g][c] = *(const f16x8*)&hA[g][ln][32*c + 8*q];

    const unsigned short* p2 = P2 + ((size_t)((r*16 + TT*wv)*8)*64 + lane)*8;
    #pragma unroll
    for (int tt = 0; tt < TT; ++tt) {
      f16x8 a2[8];
      #pragma unroll
      for (int c = 0; c < 8; ++c)
        a2[c] = *(const f16x8*)(p2 + (size_t)(tt*8 + c)*512);
      int f0 = (TT*wv + tt)*16 + 4*q;
      #pragma unroll
      for (int g = 0; g < NG; ++g) {
        floatx4 acc = bb2c[tt];
        #pragma unroll
        for (int c = 0; c < 8; ++c) acc = mfma16f(a2[c], Bf[g][c], acc);
        uint2v w = { gelu2(acc[0], acc[1]), gelu2(acc[2], acc[3]) };
        *(uint2v*)&hB[g][ln][f0] = w;
      }
    }
    __syncthreads();                       // (C) h2 ready

    // -------- prefetch next round's a1/bb1/bb2 (hides under L3 + barrier D)
    if (r < 63) {
      const unsigned short* p1n = P1 + ((size_t)((r+1)*16 + TT*wv)*64 + lane)*8;
      #pragma unroll
      for (int tt = 0; tt < TT; ++tt) {
        a1c[tt]  = *(const f16x8*)(p1n + (size_t)tt*512);
        bb1c[tt] = *(const floatx4*)(b1 + (r+1)*256 + (TT*wv + tt)*16 + 4*q);
        bb2c[tt] = *(const floatx4*)(b2 + (r+1)*256 + (TT*wv + tt)*16 + 4*q);
      }
    }

    // -------- Layer 3 (distributed; SIMD-parity-balanced wave pair) --------
    // a3/bb3 loaded inside the branch: contained live range, no spill.
    if (wv == l3w || wv == l3w + 1) {
      const int g = wv - l3w;
      const unsigned short* p3 = P3 + ((size_t)(r*8)*64 + lane)*8;
      f16x8 a3[8];
      #pragma unroll
      for (int c = 0; c < 8; ++c) a3[c] = *(const f16x8*)(p3 + (size_t)c*512);
      floatx4 s = *(const floatx4*)(b3 + r*16 + 4*q);
      #pragma unroll
      for (int c = 0; c < 8; ++c) {
        f16x8 bh = *(const f16x8*)&hB[g][ln][32*c + 8*q];
        s = mfma16f(a3[c], bh, s);
      }
      if (r == 63) {
        *(floatx4*)(out + (size_t)(row0 + g*16 + ln)*16 + 4*q) = s;
      } else {
        // state write: RTE scalar casts (64-round chain sensitivity)
        ushort4v h4;
        #pragma unroll
        for (int e = 0; e < 4; ++e) h4[e] = f16bits(s[e]);
        *(ushort4v*)&xh[g][ln][4*q] = h4;
      }
    }
    // word + rinfo for next round: scatter wave (other SIMD pair)
    if (wv == scw && lane < NG*16 && r < 63) {
      int g = lane >> 4, n = lane & 15, rrow = lane;
      int sc = c_sched[r+1];
      float i0 = (float)(r+1) * 0.015625f;   // exact in fp16
      unsigned short i1b = f16bits(c_shift[r+1] / 25.0f);
      #pragma unroll
      for (int j = 0; j < 4; ++j) xh[g][n][16+j] = msgb[rrow][4*sc+j];
      xh[g][n][20] = f16bits(i0);
      xh[g][n][21] = i1b;
    }
    if (r < 63) __syncthreads();           // (D) x ready for next L1
  }
}

// ---------------------------------------------------------------------------
extern "C" void kernel_launch(void* const* d_in, const int* in_sizes, int n_in,
                              void* d_out, int out_size, void* d_ws, size_t ws_size,
                              hipStream_t stream) {
  const float* msg = (const float*)d_in[0];
  const float* st0 = (const float*)d_in[1];
  const float* W1  = (const float*)d_in[2];
  const float* b1  = (const float*)d_in[3];
  const float* W2  = (const float*)d_in[4];
  const float* b2  = (const float*)d_in[5];
  const float* W3  = (const float*)d_in[6];
  const float* b3  = (const float*)d_in[7];
  float* out = (float*)d_out;
  (void)in_sizes; (void)n_in; (void)out_size; (void)ws_size;

  unsigned short* P = (unsigned short*)d_ws;
  const int totalGroups = N1G + N2G + N3G;   // 622592
  pack_w<<<(totalGroups + 255) / 256, 256, 0, stream>>>(W1, W2, W3, P);
  md5_main<<<512, 512, 0, stream>>>(msg, st0, b1, b2, b3, P, out);
}